// Round 1
// baseline (31.817 us; speedup 1.0000x reference)
//
#include <hip/hip_runtime.h>

#define B_  32
#define T_  256
#define D_  384
#define ML_ 2048

// Kernel 1: per-batch cumsum (LDS scan) + scatter position->token index table.
// idxtab[b*ML_ + p] = token index t covering output position p, or -1 if p >= mel_len.
__global__ void lr_idx_kernel(const int* __restrict__ dur,
                              int* __restrict__ idxtab,
                              float* __restrict__ mel_out,
                              const int* __restrict__ max_len_p) {
    const int b = blockIdx.x;
    const int t = threadIdx.x;
    __shared__ int cs[T_];

    cs[t] = dur[b * T_ + t];
    __syncthreads();

    // Hillis-Steele inclusive scan over 256 elements (8 steps).
    #pragma unroll
    for (int off = 1; off < T_; off <<= 1) {
        int v = (t >= off) ? cs[t - off] : 0;
        __syncthreads();
        cs[t] += v;
        __syncthreads();
    }

    const int end   = cs[t];
    const int start = (t == 0) ? 0 : cs[t - 1];
    const int total = cs[T_ - 1];
    const int cap   = max_len_p[0];          // == ML_ for this problem
    const int mel   = min(total, cap);

    if (t == 0) mel_out[b] = (float)mel;     // tail of d_out, read back as float32

    // Fill sentinel -1 (positions >= mel_len -> zeros), then scatter token ids.
    for (int p = t; p < ML_; p += T_) idxtab[b * ML_ + p] = -1;
    __syncthreads();                         // order -1 fill before scatter (block-local)

    const int e2 = min(end, ML_);
    for (int p = start; p < e2; ++p) idxtab[b * ML_ + p] = t;
}

// Kernel 2: gather rows of x into out, float4-vectorized, grid-stride.
__global__ void lr_gather_kernel(const float4* __restrict__ x4,
                                 const int* __restrict__ idxtab,
                                 float4* __restrict__ out4) {
    const int rowsz = D_ / 4;                              // 96 float4 per row
    const unsigned N = (unsigned)B_ * ML_ * rowsz;         // 6,291,456
    const unsigned stride = gridDim.x * blockDim.x;

    for (unsigned i = blockIdx.x * blockDim.x + threadIdx.x; i < N; i += stride) {
        const unsigned row  = i / rowsz;                   // b*ML_ + p
        const unsigned lane = i - row * rowsz;
        const int idx = idxtab[row];
        float4 v;
        if (idx >= 0) {
            const unsigned b = row >> 11;                  // row / ML_
            v = x4[(b * T_ + (unsigned)idx) * rowsz + lane];
        } else {
            v = make_float4(0.f, 0.f, 0.f, 0.f);
        }
        out4[i] = v;                                       // coalesced
    }
}

extern "C" void kernel_launch(void* const* d_in, const int* in_sizes, int n_in,
                              void* d_out, int out_size, void* d_ws, size_t ws_size,
                              hipStream_t stream) {
    const float* x       = (const float*)d_in[0];
    const int*   dur     = (const int*)d_in[1];
    const int*   max_len = (const int*)d_in[2];
    float*       out     = (float*)d_out;
    int*         idxtab  = (int*)d_ws;                     // B_*ML_*4 = 256 KiB

    float* mel_out = out + (size_t)B_ * ML_ * D_;          // tail: B_ floats

    lr_idx_kernel<<<B_, T_, 0, stream>>>(dur, idxtab, mel_out, max_len);
    lr_gather_kernel<<<2048, 256, 0, stream>>>((const float4*)x, idxtab, (float4*)out);
}

// Round 2
// 24.792 us; speedup vs baseline: 1.2834x; 1.2834x over previous
//
#include <hip/hip_runtime.h>

#define B_  32
#define T_  256
#define D_  384
#define ML_ 2048
#define ROWS_PER_BLK 32
#define CHUNKS (ML_ / ROWS_PER_BLK)   // 64 chunks per batch

// One fused kernel: each block re-computes the per-batch cumsum in LDS
// (dur is 32 KB total -> L2-resident across all 2048 blocks), binary-searches
// the token index for its 32 output rows, then does the coalesced row
// gather/write. No inter-kernel dependency, no idxtab round-trip.
__global__ __launch_bounds__(256) void lr_fused_kernel(
    const float4* __restrict__ x4,
    const int*    __restrict__ dur,
    const int*    __restrict__ max_len_p,
    float4*       __restrict__ out4,
    float*        __restrict__ mel_out)
{
    const int blk   = blockIdx.x;
    const int b     = blk >> 6;            // / CHUNKS
    const int chunk = blk & (CHUNKS - 1);
    const int tid   = threadIdx.x;

    __shared__ int cs[T_];
    __shared__ int ridx[ROWS_PER_BLK];

    cs[tid] = dur[b * T_ + tid];
    __syncthreads();

    // Hillis-Steele inclusive scan, 8 steps (stride-1 int: 2-way bank alias, free).
    #pragma unroll
    for (int off = 1; off < T_; off <<= 1) {
        int v = (tid >= off) ? cs[tid - off] : 0;
        __syncthreads();
        cs[tid] += v;
        __syncthreads();
    }

    const int total = cs[T_ - 1];
    const int mel   = min(total, max_len_p[0]);
    if (chunk == 0 && tid == 0) mel_out[b] = (float)mel;

    // Threads 0..31: searchsorted(csum, pos, side='right') for this chunk's rows.
    if (tid < ROWS_PER_BLK) {
        const int pos = chunk * ROWS_PER_BLK + tid;
        int r = -1;
        if (pos < mel) {                   // pos < mel <= total => result <= T_-1
            int lo = 0, hi = T_;           // find first t with cs[t] > pos
            #pragma unroll
            for (int s = 0; s < 8; ++s) {
                int mid = (lo + hi) >> 1;
                if (cs[mid] <= pos) lo = mid + 1; else hi = mid;
            }
            r = min(lo, T_ - 1);           // matches jnp.clip(idx, 0, T-1)
        }
        ridx[tid] = r;
    }
    __syncthreads();

    // Gather + write: 32 rows x 96 float4 = 3072 float4, 12 per thread, coalesced.
    const int rowsz = D_ / 4;                                   // 96
    const float4* xb = x4 + (size_t)b * T_ * rowsz;
    float4* ob = out4 + ((size_t)b * ML_ + (size_t)chunk * ROWS_PER_BLK) * rowsz;
    const int N = ROWS_PER_BLK * rowsz;                         // 3072

    #pragma unroll 4
    for (int i = tid; i < N; i += 256) {
        const int rl   = i / rowsz;        // compile-time magic div
        const int lane = i - rl * rowsz;
        const int idx  = ridx[rl];
        float4 v = (idx >= 0) ? xb[idx * rowsz + lane]
                              : make_float4(0.f, 0.f, 0.f, 0.f);
        ob[i] = v;
    }
}

extern "C" void kernel_launch(void* const* d_in, const int* in_sizes, int n_in,
                              void* d_out, int out_size, void* d_ws, size_t ws_size,
                              hipStream_t stream) {
    const float* x       = (const float*)d_in[0];
    const int*   dur     = (const int*)d_in[1];
    const int*   max_len = (const int*)d_in[2];
    float*       out     = (float*)d_out;
    float*       mel_out = out + (size_t)B_ * ML_ * D_;         // tail: B_ floats

    lr_fused_kernel<<<B_ * CHUNKS, 256, 0, stream>>>(
        (const float4*)x, dur, max_len, (float4*)out, mel_out);
}